// Round 1
// baseline (807.161 us; speedup 1.0000x reference)
//
#include <hip/hip_runtime.h>

#define N_NODES 20000
#define N_EDGES 200000
#define ETOT    (N_EDGES + N_NODES)
#define F_IN    20
#define HID     128
#define HEADS   4
#define FTOT    (HEADS * HID)   // 512
#define LAYERS  4
#define NGRAPH  32
#define NEG_SLOPE 0.2f

// ---------------- CSR build (dst is layer-invariant) ----------------

__global__ void k_hist(const int* __restrict__ ei, int* __restrict__ deg) {
    int i = blockIdx.x * blockDim.x + threadIdx.x;
    if (i >= ETOT) return;
    int d = (i < N_EDGES) ? ei[N_EDGES + i] : (i - N_EDGES);
    atomicAdd(&deg[d], 1);
}

__global__ __launch_bounds__(1024) void k_scan(const int* __restrict__ deg, int* __restrict__ off) {
    __shared__ int buf[1024];
    __shared__ int carry;
    int tid = threadIdx.x;
    if (tid == 0) carry = 0;
    __syncthreads();
    for (int base = 0; base < N_NODES; base += 1024) {
        int idx = base + tid;
        int v = (idx < N_NODES) ? deg[idx] : 0;
        buf[tid] = v;
        __syncthreads();
        for (int s = 1; s < 1024; s <<= 1) {
            int t = (tid >= s) ? buf[tid - s] : 0;
            __syncthreads();
            buf[tid] += t;
            __syncthreads();
        }
        if (idx < N_NODES) off[idx] = carry + buf[tid] - v;  // exclusive
        __syncthreads();
        if (tid == 0) carry += buf[1023];
        __syncthreads();
    }
    if (tid == 0) off[N_NODES] = carry;
}

__global__ void k_scatter(const int* __restrict__ ei, const int* __restrict__ off,
                          int* __restrict__ cur, int* __restrict__ csr_src) {
    int i = blockIdx.x * blockDim.x + threadIdx.x;
    if (i >= ETOT) return;
    int s, d;
    if (i < N_EDGES) { s = ei[i]; d = ei[N_EDGES + i]; }
    else             { s = d = i - N_EDGES; }
    int pos = off[d] + atomicAdd(&cur[d], 1);
    csr_src[pos] = s;
}

// ---------------- input projection: h = relu(x @ W_in + b_in) ----------------

__global__ __launch_bounds__(256) void k_inproj(const float* __restrict__ x,
                                                const float* __restrict__ W,
                                                const float* __restrict__ b,
                                                float* __restrict__ h) {
    __shared__ float xs[2][F_IN];
    int tid = threadIdx.x;
    int node0 = blockIdx.x * 2;
    if (tid < 2 * F_IN) {
        int r = tid / F_IN, k = tid % F_IN;
        int nd = node0 + r;
        xs[r][k] = (nd < N_NODES) ? x[nd * F_IN + k] : 0.f;
    }
    __syncthreads();
    int ln = tid >> 7;
    int c  = tid & 127;
    int node = node0 + ln;
    if (node >= N_NODES) return;
    float s = b[c];
    #pragma unroll
    for (int k = 0; k < F_IN; ++k) s += xs[ln][k] * W[k * HID + c];
    h[(size_t)node * HID + c] = fmaxf(s, 0.f);
}

// ---------------- GEMM: xl[N,512] = h[N,128] @ W[128,512] ----------------
// 64x64 tile, 256 threads, 4x4 microtile, K=128 in one shot.

__global__ __launch_bounds__(256) void k_gemm(const float* __restrict__ A,
                                              const float* __restrict__ B,
                                              float* __restrict__ C) {
    __shared__ float As[64][132];   // row-major, pad 132 -> conflict-free reads
    __shared__ float Bs[128][64];
    int row0 = blockIdx.x * 64;
    int col0 = blockIdx.y * 64;
    int tid = threadIdx.x;
    {   // stage A: 64 x 128
        int kq = (tid & 31) << 2;
        int r0 = tid >> 5;
        #pragma unroll
        for (int rr = 0; rr < 8; ++rr) {
            int r = r0 + rr * 8;
            int row = row0 + r;
            float4 v = make_float4(0.f, 0.f, 0.f, 0.f);
            if (row < N_NODES) v = *(const float4*)(A + (size_t)row * HID + kq);
            *(float4*)&As[r][kq] = v;
        }
    }
    {   // stage B: 128 x 64
        int c4 = (tid & 15) << 2;
        int k0 = tid >> 4;
        #pragma unroll
        for (int kk = 0; kk < 8; ++kk) {
            int k = k0 + kk * 16;
            *(float4*)&Bs[k][c4] = *(const float4*)(B + (size_t)k * FTOT + col0 + c4);
        }
    }
    __syncthreads();
    int tx = tid & 15, ty = tid >> 4;
    float acc[4][4] = {};
    #pragma unroll 2
    for (int k = 0; k < 128; k += 4) {
        float4 a[4], bb[4];
        #pragma unroll
        for (int i = 0; i < 4; ++i) a[i] = *(const float4*)&As[ty * 4 + i][k];
        #pragma unroll
        for (int j = 0; j < 4; ++j) bb[j] = *(const float4*)&Bs[k + j][tx * 4];
        #pragma unroll
        for (int i = 0; i < 4; ++i) {
            const float* av = (const float*)&a[i];
            #pragma unroll
            for (int j = 0; j < 4; ++j) {
                acc[i][0] += av[j] * bb[j].x;
                acc[i][1] += av[j] * bb[j].y;
                acc[i][2] += av[j] * bb[j].z;
                acc[i][3] += av[j] * bb[j].w;
            }
        }
    }
    #pragma unroll
    for (int i = 0; i < 4; ++i) {
        int row = row0 + ty * 4 + i;
        if (row < N_NODES) {
            float4 v = make_float4(acc[i][0], acc[i][1], acc[i][2], acc[i][3]);
            *(float4*)(C + (size_t)row * FTOT + col0 + tx * 4) = v;
        }
    }
}

// ---------------- attention coefficients per node ----------------
// wave per node: al_src[n,h] = dot(xl[n,h,:], att_src[h,:]); same for dst.

__global__ __launch_bounds__(256) void k_att(const float* __restrict__ xl,
                                             const float* __restrict__ asrc,
                                             const float* __restrict__ adst,
                                             float* __restrict__ al_s,
                                             float* __restrict__ al_d) {
    int wid  = threadIdx.x >> 6;
    int lane = threadIdx.x & 63;
    int node = blockIdx.x * 4 + wid;
    if (node >= N_NODES) return;
    int base = lane * 8;                 // global channel in [0,512)
    const float4* xr = (const float4*)(xl + (size_t)node * FTOT + base);
    float4 x0 = xr[0], x1 = xr[1];
    const float4* s4 = (const float4*)(asrc + base);
    const float4* d4 = (const float4*)(adst + base);
    float4 s0 = s4[0], s1 = s4[1], dd0 = d4[0], dd1 = d4[1];
    float ps = x0.x*s0.x + x0.y*s0.y + x0.z*s0.z + x0.w*s0.w
             + x1.x*s1.x + x1.y*s1.y + x1.z*s1.z + x1.w*s1.w;
    float pd = x0.x*dd0.x + x0.y*dd0.y + x0.z*dd0.z + x0.w*dd0.w
             + x1.x*dd1.x + x1.y*dd1.y + x1.z*dd1.z + x1.w*dd1.w;
    #pragma unroll
    for (int m = 1; m < 16; m <<= 1) {
        ps += __shfl_xor(ps, m, 64);
        pd += __shfl_xor(pd, m, 64);
    }
    if ((lane & 15) == 0) {
        int hh = lane >> 4;
        al_s[node * HEADS + hh] = ps;
        al_d[node * HEADS + hh] = pd;
    }
}

// ---------------- edge aggregation (segment softmax + weighted sum) ----------------
// wave per node; lane covers channels lane*8..+7 (head = lane>>4).

__global__ __launch_bounds__(256) void k_agg(const float* __restrict__ xl,
                                             const float* __restrict__ al_s,
                                             const float* __restrict__ al_d,
                                             const int* __restrict__ csr_off,
                                             const int* __restrict__ csr_src,
                                             const float* __restrict__ bias,
                                             float* __restrict__ h) {
    int wid  = threadIdx.x >> 6;
    int lane = threadIdx.x & 63;
    int node = blockIdx.x * 4 + wid;
    if (node >= N_NODES) return;
    int hh = lane >> 4;
    int e0 = csr_off[node], e1 = csr_off[node + 1];
    float ald = al_d[node * HEADS + hh];

    // pass A: online (m, z) for this head, edge-parallel over 16 lanes
    float m = -1e30f, z = 0.f;
    for (int e = e0 + (lane & 15); e < e1; e += 16) {
        int s = csr_src[e];
        float ev = al_s[s * HEADS + hh] + ald;
        ev = ev > 0.f ? ev : NEG_SLOPE * ev;
        float mn = fmaxf(m, ev);
        z = z * __expf(m - mn) + __expf(ev - mn);
        m = mn;
    }
    #pragma unroll
    for (int msk = 1; msk < 16; msk <<= 1) {
        float m2 = __shfl_xor(m, msk, 64);
        float z2 = __shfl_xor(z, msk, 64);
        float mn = fmaxf(m, m2);
        z = z * __expf(m - mn) + z2 * __expf(m2 - mn);
        m = mn;
    }
    float zinv = 1.f / (z + 1e-16f);

    // pass B: accumulate alpha * xl[src]
    float acc[8] = {};
    for (int e = e0; e < e1; ++e) {
        int s = csr_src[e];
        float ev = al_s[s * HEADS + hh] + ald;
        ev = ev > 0.f ? ev : NEG_SLOPE * ev;
        float alpha = __expf(ev - m) * zinv;
        const float4* xr = (const float4*)(xl + (size_t)s * FTOT + lane * 8);
        float4 v0 = xr[0], v1 = xr[1];
        acc[0] += alpha * v0.x; acc[1] += alpha * v0.y;
        acc[2] += alpha * v0.z; acc[3] += alpha * v0.w;
        acc[4] += alpha * v1.x; acc[5] += alpha * v1.y;
        acc[6] += alpha * v1.z; acc[7] += alpha * v1.w;
    }
    // sum over heads (lanes l, l^16, l^32, l^48 share channel-within-head)
    #pragma unroll
    for (int j = 0; j < 8; ++j) {
        acc[j] += __shfl_xor(acc[j], 16, 64);
        acc[j] += __shfl_xor(acc[j], 32, 64);
    }
    if (lane < 16) {
        int c = lane * 8;
        float4 hv0 = *(const float4*)(h + (size_t)node * HID + c);
        float4 hv1 = *(const float4*)(h + (size_t)node * HID + c + 4);
        float4 b0 = *(const float4*)(bias + c);
        float4 b1 = *(const float4*)(bias + c + 4);
        float4 o0, o1;
        o0.x = fmaxf(acc[0] * 0.25f + b0.x, 0.f) + hv0.x;
        o0.y = fmaxf(acc[1] * 0.25f + b0.y, 0.f) + hv0.y;
        o0.z = fmaxf(acc[2] * 0.25f + b0.z, 0.f) + hv0.z;
        o0.w = fmaxf(acc[3] * 0.25f + b0.w, 0.f) + hv0.w;
        o1.x = fmaxf(acc[4] * 0.25f + b1.x, 0.f) + hv1.x;
        o1.y = fmaxf(acc[5] * 0.25f + b1.y, 0.f) + hv1.y;
        o1.z = fmaxf(acc[6] * 0.25f + b1.z, 0.f) + hv1.z;
        o1.w = fmaxf(acc[7] * 0.25f + b1.w, 0.f) + hv1.w;
        *(float4*)(h + (size_t)node * HID + c)     = o0;
        *(float4*)(h + (size_t)node * HID + c + 4) = o1;
    }
}

// ---------------- pooling + MLP ----------------

__global__ void k_cnt(const int* __restrict__ batch, int* __restrict__ gcnt) {
    int i = blockIdx.x * blockDim.x + threadIdx.x;
    if (i < N_NODES) atomicAdd(&gcnt[batch[i]], 1);
}

__global__ __launch_bounds__(128) void k_pool(const float* __restrict__ h,
                                              const int* __restrict__ gcnt,
                                              float* __restrict__ pooled) {
    int g = blockIdx.y;
    int slice = blockIdx.x;      // 0..7
    int tid = threadIdx.x;       // 0..127
    __shared__ int sh_start, sh_cnt;
    if (tid == 0) {
        int st = 0;
        for (int i = 0; i < g; ++i) st += gcnt[i];
        sh_start = st; sh_cnt = gcnt[g];
    }
    __syncthreads();
    int start = sh_start, cnt = sh_cnt;
    int per = (cnt + 7) / 8;
    int r0 = slice * per, r1 = min(r0 + per, cnt);
    float s0 = 0.f, s1 = 0.f, s2 = 0.f, s3 = 0.f;
    int r = r0;
    for (; r + 3 < r1; r += 4) {
        s0 += h[(size_t)(start + r)     * HID + tid];
        s1 += h[(size_t)(start + r + 1) * HID + tid];
        s2 += h[(size_t)(start + r + 2) * HID + tid];
        s3 += h[(size_t)(start + r + 3) * HID + tid];
    }
    for (; r < r1; ++r) s0 += h[(size_t)(start + r) * HID + tid];
    float s = (s0 + s1) + (s2 + s3);
    if (r1 > r0) atomicAdd(&pooled[g * HID + tid], s);
}

__global__ __launch_bounds__(256) void k_mlp(const float* __restrict__ pooled,
                                             const int* __restrict__ gcnt,
                                             const float* __restrict__ W1, const float* __restrict__ b1,
                                             const float* __restrict__ W2, const float* __restrict__ b2,
                                             const float* __restrict__ W3, const float* __restrict__ b3,
                                             float* __restrict__ out) {
    __shared__ float g[NGRAPH][HID];
    __shared__ float t1[NGRAPH][64];
    __shared__ float t2[NGRAPH][64];
    int tid = threadIdx.x;
    for (int i = tid; i < NGRAPH * HID; i += 256) {
        int gr = i >> 7;
        float inv = 1.f / fmaxf((float)gcnt[gr], 1.f);
        g[gr][i & 127] = pooled[i] * inv;
    }
    __syncthreads();
    for (int i = tid; i < NGRAPH * 64; i += 256) {
        int r = i >> 6, c = i & 63;
        float s = b1[c];
        #pragma unroll 4
        for (int k = 0; k < HID; ++k) s += g[r][k] * W1[k * 64 + c];
        t1[r][c] = fmaxf(s, 0.f);
    }
    __syncthreads();
    for (int i = tid; i < NGRAPH * 64; i += 256) {
        int r = i >> 6, c = i & 63;
        float s = b2[c];
        #pragma unroll 4
        for (int k = 0; k < 64; ++k) s += t1[r][k] * W2[k * 64 + c];
        t2[r][c] = fmaxf(s, 0.f);
    }
    __syncthreads();
    for (int i = tid; i < NGRAPH * 32; i += 256) {
        int r = i >> 5, c = i & 31;
        float s = b3[c];
        #pragma unroll 4
        for (int k = 0; k < 64; ++k) s += t2[r][k] * W3[k * 32 + c];
        out[i] = s;
    }
}

// ---------------- launcher ----------------

extern "C" void kernel_launch(void* const* d_in, const int* in_sizes, int n_in,
                              void* d_out, int out_size, void* d_ws, size_t ws_size,
                              hipStream_t stream) {
    const float* x       = (const float*)d_in[0];
    const int*   ei      = (const int*)d_in[1];
    const int*   batch   = (const int*)d_in[2];
    const float* W_in    = (const float*)d_in[3];
    const float* b_in    = (const float*)d_in[4];
    const float* gat_W   = (const float*)d_in[5];
    const float* att_src = (const float*)d_in[6];
    const float* att_dst = (const float*)d_in[7];
    const float* gat_b   = (const float*)d_in[8];
    const float* W1 = (const float*)d_in[9];
    const float* b1 = (const float*)d_in[10];
    const float* W2 = (const float*)d_in[11];
    const float* b2 = (const float*)d_in[12];
    const float* W3 = (const float*)d_in[13];
    const float* b3 = (const float*)d_in[14];
    float* out = (float*)d_out;

    char* ws = (char*)d_ws;
    size_t o = 0;
    auto alloc = [&](size_t nbytes) -> void* {
        void* p = ws + o;
        o += (nbytes + 255) & ~(size_t)255;
        return p;
    };
    int* deg      = (int*)alloc((size_t)2 * N_NODES * 4);      // deg | cur
    int* cur      = deg + N_NODES;
    int* gcnt     = (int*)alloc((size_t)(NGRAPH + NGRAPH * HID) * 4);  // gcnt | pooled
    float* pooled = (float*)(gcnt + NGRAPH);
    int* csr_off  = (int*)alloc((size_t)(N_NODES + 1) * 4);
    int* csr_src  = (int*)alloc((size_t)ETOT * 4);
    float* h      = (float*)alloc((size_t)N_NODES * HID * 4);
    float* xl     = (float*)alloc((size_t)N_NODES * FTOT * 4);
    float* al_s   = (float*)alloc((size_t)N_NODES * HEADS * 4);
    float* al_d   = (float*)alloc((size_t)N_NODES * HEADS * 4);

    hipMemsetAsync(deg, 0, (size_t)2 * N_NODES * 4, stream);
    hipMemsetAsync(gcnt, 0, (size_t)(NGRAPH + NGRAPH * HID) * 4, stream);

    k_hist<<<(ETOT + 255) / 256, 256, 0, stream>>>(ei, deg);
    k_scan<<<1, 1024, 0, stream>>>(deg, csr_off);
    k_scatter<<<(ETOT + 255) / 256, 256, 0, stream>>>(ei, csr_off, cur, csr_src);

    k_inproj<<<(N_NODES + 1) / 2, 256, 0, stream>>>(x, W_in, b_in, h);

    for (int l = 0; l < LAYERS; ++l) {
        k_gemm<<<dim3((N_NODES + 63) / 64, FTOT / 64), 256, 0, stream>>>(
            h, gat_W + (size_t)l * HID * FTOT, xl);
        k_att<<<(N_NODES + 3) / 4, 256, 0, stream>>>(
            xl, att_src + (size_t)l * HEADS * HID, att_dst + (size_t)l * HEADS * HID, al_s, al_d);
        k_agg<<<(N_NODES + 3) / 4, 256, 0, stream>>>(
            xl, al_s, al_d, csr_off, csr_src, gat_b + (size_t)l * HID, h);
    }

    k_cnt<<<(N_NODES + 255) / 256, 256, 0, stream>>>(batch, gcnt);
    k_pool<<<dim3(8, NGRAPH), 128, 0, stream>>>(h, gcnt, pooled);
    k_mlp<<<1, 256, 0, stream>>>(pooled, gcnt, W1, b1, W2, b2, W3, b3, out);
}

// Round 3
// 658.254 us; speedup vs baseline: 1.2262x; 1.2262x over previous
//
#include <hip/hip_runtime.h>

#define N_NODES 20000
#define N_EDGES 200000
#define ETOT    (N_EDGES + N_NODES)
#define F_IN    20
#define HID     128
#define HEADS   4
#define FTOT    (HEADS * HID)   // 512
#define LAYERS  4
#define NGRAPH  32
#define NEG_SLOPE 0.2f

// ---------------- CSR build (dst is layer-invariant) ----------------

__global__ void k_hist(const int* __restrict__ ei, int* __restrict__ deg) {
    int i = blockIdx.x * blockDim.x + threadIdx.x;
    if (i >= ETOT) return;
    int d = (i < N_EDGES) ? ei[N_EDGES + i] : (i - N_EDGES);
    atomicAdd(&deg[d], 1);
}

// single-block exclusive scan of deg[0..N) -> off, shfl-based (few barriers)
__global__ __launch_bounds__(1024) void k_scan(const int* __restrict__ deg, int* __restrict__ off) {
    __shared__ int wsum[16];
    __shared__ int carry_s;
    int tid  = threadIdx.x;
    int lane = tid & 63, wv = tid >> 6;
    if (tid == 0) carry_s = 0;
    __syncthreads();
    for (int base = 0; base < N_NODES; base += 1024) {
        int idx = base + tid;
        int v = (idx < N_NODES) ? deg[idx] : 0;
        // wave-inclusive scan
        int x = v;
        #pragma unroll
        for (int s = 1; s < 64; s <<= 1) {
            int t = __shfl_up(x, s, 64);
            if (lane >= s) x += t;
        }
        if (lane == 63) wsum[wv] = x;
        __syncthreads();
        if (wv == 0) {
            int ws = (lane < 16) ? wsum[lane] : 0;
            #pragma unroll
            for (int s = 1; s < 16; s <<= 1) {
                int t = __shfl_up(ws, s, 64);
                if (lane >= s) ws += t;
            }
            if (lane < 16) wsum[lane] = ws;   // inclusive wave sums
        }
        __syncthreads();
        int wprev = (wv == 0) ? 0 : wsum[wv - 1];
        int incl  = carry_s + wprev + x;      // inclusive within whole array
        if (idx < N_NODES) off[idx] = incl - v;
        __syncthreads();                      // all reads of carry_s done
        if (tid == 1023) carry_s = incl;
        __syncthreads();
    }
    if (threadIdx.x == 0) off[N_NODES] = carry_s;
}

__global__ void k_scatter(const int* __restrict__ ei, const int* __restrict__ off,
                          int* __restrict__ cur, int* __restrict__ csr_src) {
    int i = blockIdx.x * blockDim.x + threadIdx.x;
    if (i >= ETOT) return;
    int s, d;
    if (i < N_EDGES) { s = ei[i]; d = ei[N_EDGES + i]; }
    else             { s = d = i - N_EDGES; }
    int pos = off[d] + atomicAdd(&cur[d], 1);
    csr_src[pos] = s;
}

// ---------------- graph boundaries (batch is sorted): no atomics ----------------

__global__ void k_bounds(const int* __restrict__ batch, int* __restrict__ gstart) {
    int i = blockIdx.x * blockDim.x + threadIdx.x;
    if (i >= N_NODES) return;
    int b = batch[i];
    int prev = (i == 0) ? -1 : batch[i - 1];
    for (int g = prev + 1; g <= b; ++g) gstart[g] = i;
    if (i == N_NODES - 1) {
        for (int g = b + 1; g <= NGRAPH; ++g) gstart[g] = N_NODES;
    }
}

// ---------------- input projection: h = relu(x @ W_in + b_in) ----------------

__global__ __launch_bounds__(256) void k_inproj(const float* __restrict__ x,
                                                const float* __restrict__ W,
                                                const float* __restrict__ b,
                                                float* __restrict__ h) {
    __shared__ float xs[2][F_IN];
    int tid = threadIdx.x;
    int node0 = blockIdx.x * 2;
    if (tid < 2 * F_IN) {
        int r = tid / F_IN, k = tid % F_IN;
        int nd = node0 + r;
        xs[r][k] = (nd < N_NODES) ? x[nd * F_IN + k] : 0.f;
    }
    __syncthreads();
    int ln = tid >> 7;
    int c  = tid & 127;
    int node = node0 + ln;
    if (node >= N_NODES) return;
    float s = b[c];
    #pragma unroll
    for (int k = 0; k < F_IN; ++k) s += xs[ln][k] * W[k * HID + c];
    h[(size_t)node * HID + c] = fmaxf(s, 0.f);
}

// ---------------- GEMM: xl[N,512] = h[N,128] @ W[128,512] ----------------

__global__ __launch_bounds__(256) void k_gemm(const float* __restrict__ A,
                                              const float* __restrict__ B,
                                              float* __restrict__ C) {
    __shared__ float As[64][132];
    __shared__ float Bs[128][64];
    int row0 = blockIdx.x * 64;
    int col0 = blockIdx.y * 64;
    int tid = threadIdx.x;
    {   // stage A: 64 x 128
        int kq = (tid & 31) << 2;
        int r0 = tid >> 5;
        #pragma unroll
        for (int rr = 0; rr < 8; ++rr) {
            int r = r0 + rr * 8;
            int row = row0 + r;
            float4 v = make_float4(0.f, 0.f, 0.f, 0.f);
            if (row < N_NODES) v = *(const float4*)(A + (size_t)row * HID + kq);
            *(float4*)&As[r][kq] = v;
        }
    }
    {   // stage B: 128 x 64
        int c4 = (tid & 15) << 2;
        int k0 = tid >> 4;
        #pragma unroll
        for (int kk = 0; kk < 8; ++kk) {
            int k = k0 + kk * 16;
            *(float4*)&Bs[k][c4] = *(const float4*)(B + (size_t)k * FTOT + col0 + c4);
        }
    }
    __syncthreads();
    int tx = tid & 15, ty = tid >> 4;
    float acc[4][4] = {};
    #pragma unroll 2
    for (int k = 0; k < 128; k += 4) {
        float4 a[4], bb[4];
        #pragma unroll
        for (int i = 0; i < 4; ++i) a[i] = *(const float4*)&As[ty * 4 + i][k];
        #pragma unroll
        for (int j = 0; j < 4; ++j) bb[j] = *(const float4*)&Bs[k + j][tx * 4];
        #pragma unroll
        for (int i = 0; i < 4; ++i) {
            const float* av = (const float*)&a[i];
            #pragma unroll
            for (int j = 0; j < 4; ++j) {
                acc[i][0] += av[j] * bb[j].x;
                acc[i][1] += av[j] * bb[j].y;
                acc[i][2] += av[j] * bb[j].z;
                acc[i][3] += av[j] * bb[j].w;
            }
        }
    }
    #pragma unroll
    for (int i = 0; i < 4; ++i) {
        int row = row0 + ty * 4 + i;
        if (row < N_NODES) {
            float4 v = make_float4(acc[i][0], acc[i][1], acc[i][2], acc[i][3]);
            *(float4*)(C + (size_t)row * FTOT + col0 + tx * 4) = v;
        }
    }
}

// ---------------- attention coefficients per node ----------------

__global__ __launch_bounds__(256) void k_att(const float* __restrict__ xl,
                                             const float* __restrict__ asrc,
                                             const float* __restrict__ adst,
                                             float* __restrict__ al_s,
                                             float* __restrict__ al_d) {
    int wid  = threadIdx.x >> 6;
    int lane = threadIdx.x & 63;
    int node = blockIdx.x * 4 + wid;
    if (node >= N_NODES) return;
    int base = lane * 8;
    const float4* xr = (const float4*)(xl + (size_t)node * FTOT + base);
    float4 x0 = xr[0], x1 = xr[1];
    const float4* s4 = (const float4*)(asrc + base);
    const float4* d4 = (const float4*)(adst + base);
    float4 s0 = s4[0], s1 = s4[1], dd0 = d4[0], dd1 = d4[1];
    float ps = x0.x*s0.x + x0.y*s0.y + x0.z*s0.z + x0.w*s0.w
             + x1.x*s1.x + x1.y*s1.y + x1.z*s1.z + x1.w*s1.w;
    float pd = x0.x*dd0.x + x0.y*dd0.y + x0.z*dd0.z + x0.w*dd0.w
             + x1.x*dd1.x + x1.y*dd1.y + x1.z*dd1.z + x1.w*dd1.w;
    #pragma unroll
    for (int m = 1; m < 16; m <<= 1) {
        ps += __shfl_xor(ps, m, 64);
        pd += __shfl_xor(pd, m, 64);
    }
    if ((lane & 15) == 0) {
        int hh = lane >> 4;
        al_s[node * HEADS + hh] = ps;
        al_d[node * HEADS + hh] = pd;
    }
}

// ---------------- edge aggregation (segment softmax + weighted sum) ----------------

__global__ __launch_bounds__(256) void k_agg(const float* __restrict__ xl,
                                             const float* __restrict__ al_s,
                                             const float* __restrict__ al_d,
                                             const int* __restrict__ csr_off,
                                             const int* __restrict__ csr_src,
                                             const float* __restrict__ bias,
                                             float* __restrict__ h) {
    int wid  = threadIdx.x >> 6;
    int lane = threadIdx.x & 63;
    int node = blockIdx.x * 4 + wid;
    if (node >= N_NODES) return;
    int hh = lane >> 4;
    int e0 = csr_off[node], e1 = csr_off[node + 1];
    float ald = al_d[node * HEADS + hh];

    float m = -1e30f, z = 0.f;
    for (int e = e0 + (lane & 15); e < e1; e += 16) {
        int s = csr_src[e];
        float ev = al_s[s * HEADS + hh] + ald;
        ev = ev > 0.f ? ev : NEG_SLOPE * ev;
        float mn = fmaxf(m, ev);
        z = z * __expf(m - mn) + __expf(ev - mn);
        m = mn;
    }
    #pragma unroll
    for (int msk = 1; msk < 16; msk <<= 1) {
        float m2 = __shfl_xor(m, msk, 64);
        float z2 = __shfl_xor(z, msk, 64);
        float mn = fmaxf(m, m2);
        z = z * __expf(m - mn) + z2 * __expf(m2 - mn);
        m = mn;
    }
    float zinv = 1.f / (z + 1e-16f);

    float acc[8] = {};
    for (int e = e0; e < e1; ++e) {
        int s = csr_src[e];
        float ev = al_s[s * HEADS + hh] + ald;
        ev = ev > 0.f ? ev : NEG_SLOPE * ev;
        float alpha = __expf(ev - m) * zinv;
        const float4* xr = (const float4*)(xl + (size_t)s * FTOT + lane * 8);
        float4 v0 = xr[0], v1 = xr[1];
        acc[0] += alpha * v0.x; acc[1] += alpha * v0.y;
        acc[2] += alpha * v0.z; acc[3] += alpha * v0.w;
        acc[4] += alpha * v1.x; acc[5] += alpha * v1.y;
        acc[6] += alpha * v1.z; acc[7] += alpha * v1.w;
    }
    #pragma unroll
    for (int j = 0; j < 8; ++j) {
        acc[j] += __shfl_xor(acc[j], 16, 64);
        acc[j] += __shfl_xor(acc[j], 32, 64);
    }
    if (lane < 16) {
        int c = lane * 8;
        float4 hv0 = *(const float4*)(h + (size_t)node * HID + c);
        float4 hv1 = *(const float4*)(h + (size_t)node * HID + c + 4);
        float4 b0 = *(const float4*)(bias + c);
        float4 b1 = *(const float4*)(bias + c + 4);
        float4 o0, o1;
        o0.x = fmaxf(acc[0] * 0.25f + b0.x, 0.f) + hv0.x;
        o0.y = fmaxf(acc[1] * 0.25f + b0.y, 0.f) + hv0.y;
        o0.z = fmaxf(acc[2] * 0.25f + b0.z, 0.f) + hv0.z;
        o0.w = fmaxf(acc[3] * 0.25f + b0.w, 0.f) + hv0.w;
        o1.x = fmaxf(acc[4] * 0.25f + b1.x, 0.f) + hv1.x;
        o1.y = fmaxf(acc[5] * 0.25f + b1.y, 0.f) + hv1.y;
        o1.z = fmaxf(acc[6] * 0.25f + b1.z, 0.f) + hv1.z;
        o1.w = fmaxf(acc[7] * 0.25f + b1.w, 0.f) + hv1.w;
        *(float4*)(h + (size_t)node * HID + c)     = o0;
        *(float4*)(h + (size_t)node * HID + c + 4) = o1;
    }
}

// ---------------- pooling + MLP ----------------

__global__ __launch_bounds__(128) void k_pool(const float* __restrict__ h,
                                              const int* __restrict__ gstart,
                                              float* __restrict__ pooled) {
    int g = blockIdx.y;
    int slice = blockIdx.x;      // 0..31
    int tid = threadIdx.x;       // 0..127
    int start = gstart[g];
    int cnt   = gstart[g + 1] - start;
    int per = (cnt + 31) / 32;
    int r0 = slice * per, r1 = min(r0 + per, cnt);
    if (r0 >= r1) return;
    float s0 = 0.f, s1 = 0.f, s2 = 0.f, s3 = 0.f;
    int r = r0;
    for (; r + 3 < r1; r += 4) {
        s0 += h[(size_t)(start + r)     * HID + tid];
        s1 += h[(size_t)(start + r + 1) * HID + tid];
        s2 += h[(size_t)(start + r + 2) * HID + tid];
        s3 += h[(size_t)(start + r + 3) * HID + tid];
    }
    for (; r < r1; ++r) s0 += h[(size_t)(start + r) * HID + tid];
    atomicAdd(&pooled[g * HID + tid], (s0 + s1) + (s2 + s3));
}

__global__ __launch_bounds__(256) void k_mlp(const float* __restrict__ pooled,
                                             const int* __restrict__ gstart,
                                             const float* __restrict__ W1, const float* __restrict__ b1,
                                             const float* __restrict__ W2, const float* __restrict__ b2,
                                             const float* __restrict__ W3, const float* __restrict__ b3,
                                             float* __restrict__ out) {
    __shared__ float g[NGRAPH][HID];
    __shared__ float t1[NGRAPH][64];
    __shared__ float t2[NGRAPH][64];
    int tid = threadIdx.x;
    for (int i = tid; i < NGRAPH * HID; i += 256) {
        int gr = i >> 7;
        float inv = 1.f / fmaxf((float)(gstart[gr + 1] - gstart[gr]), 1.f);
        g[gr][i & 127] = pooled[i] * inv;
    }
    __syncthreads();
    for (int i = tid; i < NGRAPH * 64; i += 256) {
        int r = i >> 6, c = i & 63;
        float s = b1[c];
        #pragma unroll 4
        for (int k = 0; k < HID; ++k) s += g[r][k] * W1[k * 64 + c];
        t1[r][c] = fmaxf(s, 0.f);
    }
    __syncthreads();
    for (int i = tid; i < NGRAPH * 64; i += 256) {
        int r = i >> 6, c = i & 63;
        float s = b2[c];
        #pragma unroll 4
        for (int k = 0; k < 64; ++k) s += t1[r][k] * W2[k * 64 + c];
        t2[r][c] = fmaxf(s, 0.f);
    }
    __syncthreads();
    for (int i = tid; i < NGRAPH * 32; i += 256) {
        int r = i >> 5, c = i & 31;
        float s = b3[c];
        #pragma unroll 4
        for (int k = 0; k < 64; ++k) s += t2[r][k] * W3[k * 32 + c];
        out[i] = s;
    }
}

// ---------------- launcher ----------------

extern "C" void kernel_launch(void* const* d_in, const int* in_sizes, int n_in,
                              void* d_out, int out_size, void* d_ws, size_t ws_size,
                              hipStream_t stream) {
    const float* x       = (const float*)d_in[0];
    const int*   ei      = (const int*)d_in[1];
    const int*   batch   = (const int*)d_in[2];
    const float* W_in    = (const float*)d_in[3];
    const float* b_in    = (const float*)d_in[4];
    const float* gat_W   = (const float*)d_in[5];
    const float* att_src = (const float*)d_in[6];
    const float* att_dst = (const float*)d_in[7];
    const float* gat_b   = (const float*)d_in[8];
    const float* W1 = (const float*)d_in[9];
    const float* b1 = (const float*)d_in[10];
    const float* W2 = (const float*)d_in[11];
    const float* b2 = (const float*)d_in[12];
    const float* W3 = (const float*)d_in[13];
    const float* b3 = (const float*)d_in[14];
    float* out = (float*)d_out;

    char* ws = (char*)d_ws;
    size_t o = 0;
    auto alloc = [&](size_t nbytes) -> void* {
        void* p = ws + o;
        o += (nbytes + 255) & ~(size_t)255;
        return p;
    };
    int* deg      = (int*)alloc((size_t)2 * N_NODES * 4);      // deg | cur
    int* cur      = deg + N_NODES;
    int* gstart   = (int*)alloc((size_t)(NGRAPH + 1) * 4);
    float* pooled = (float*)alloc((size_t)NGRAPH * HID * 4);
    int* csr_off  = (int*)alloc((size_t)(N_NODES + 1) * 4);
    int* csr_src  = (int*)alloc((size_t)ETOT * 4);
    float* h      = (float*)alloc((size_t)N_NODES * HID * 4);
    float* xl     = (float*)alloc((size_t)N_NODES * FTOT * 4);
    float* al_s   = (float*)alloc((size_t)N_NODES * HEADS * 4);
    float* al_d   = (float*)alloc((size_t)N_NODES * HEADS * 4);

    hipMemsetAsync(deg, 0, (size_t)2 * N_NODES * 4, stream);
    hipMemsetAsync(pooled, 0, (size_t)NGRAPH * HID * 4, stream);

    k_hist<<<(ETOT + 255) / 256, 256, 0, stream>>>(ei, deg);
    k_scan<<<1, 1024, 0, stream>>>(deg, csr_off);
    k_scatter<<<(ETOT + 255) / 256, 256, 0, stream>>>(ei, csr_off, cur, csr_src);
    k_bounds<<<(N_NODES + 255) / 256, 256, 0, stream>>>(batch, gstart);

    k_inproj<<<(N_NODES + 1) / 2, 256, 0, stream>>>(x, W_in, b_in, h);

    for (int l = 0; l < LAYERS; ++l) {
        k_gemm<<<dim3((N_NODES + 63) / 64, FTOT / 64), 256, 0, stream>>>(
            h, gat_W + (size_t)l * HID * FTOT, xl);
        k_att<<<(N_NODES + 3) / 4, 256, 0, stream>>>(
            xl, att_src + (size_t)l * HEADS * HID, att_dst + (size_t)l * HEADS * HID, al_s, al_d);
        k_agg<<<(N_NODES + 3) / 4, 256, 0, stream>>>(
            xl, al_s, al_d, csr_off, csr_src, gat_b + (size_t)l * HID, h);
    }

    k_pool<<<dim3(32, NGRAPH), 128, 0, stream>>>(h, gstart, pooled);
    k_mlp<<<1, 256, 0, stream>>>(pooled, gstart, W1, b1, W2, b2, W3, b3, out);
}

// Round 4
// 531.535 us; speedup vs baseline: 1.5185x; 1.2384x over previous
//
#include <hip/hip_runtime.h>

#define N_NODES 20000
#define N_EDGES 200000
#define ETOT    (N_EDGES + N_NODES)
#define F_IN    20
#define HID     128
#define HEADS   4
#define FTOT    (HEADS * HID)   // 512
#define LAYERS  4
#define NGRAPH  32
#define NEG_SLOPE 0.2f

typedef __attribute__((ext_vector_type(8))) unsigned short ushortx8;

static __device__ __forceinline__ unsigned short f2bf(float f) {
    unsigned u = __float_as_uint(f);
    u += 0x7FFFu + ((u >> 16) & 1u);   // round-to-nearest-even
    return (unsigned short)(u >> 16);
}
static __device__ __forceinline__ float bf2f(unsigned short s) {
    return __uint_as_float(((unsigned)s) << 16);
}

// ---------------- CSR build (dst is layer-invariant) ----------------

__global__ void k_hist(const int* __restrict__ ei, int* __restrict__ deg) {
    int i = blockIdx.x * blockDim.x + threadIdx.x;
    if (i >= ETOT) return;
    int d = (i < N_EDGES) ? ei[N_EDGES + i] : (i - N_EDGES);
    atomicAdd(&deg[d], 1);
}

__global__ __launch_bounds__(1024) void k_scan(const int* __restrict__ deg, int* __restrict__ off) {
    __shared__ int wsum[16];
    __shared__ int carry_s;
    int tid  = threadIdx.x;
    int lane = tid & 63, wv = tid >> 6;
    if (tid == 0) carry_s = 0;
    __syncthreads();
    for (int base = 0; base < N_NODES; base += 1024) {
        int idx = base + tid;
        int v = (idx < N_NODES) ? deg[idx] : 0;
        int x = v;
        #pragma unroll
        for (int s = 1; s < 64; s <<= 1) {
            int t = __shfl_up(x, s, 64);
            if (lane >= s) x += t;
        }
        if (lane == 63) wsum[wv] = x;
        __syncthreads();
        if (wv == 0) {
            int ws = (lane < 16) ? wsum[lane] : 0;
            #pragma unroll
            for (int s = 1; s < 16; s <<= 1) {
                int t = __shfl_up(ws, s, 64);
                if (lane >= s) ws += t;
            }
            if (lane < 16) wsum[lane] = ws;
        }
        __syncthreads();
        int wprev = (wv == 0) ? 0 : wsum[wv - 1];
        int incl  = carry_s + wprev + x;
        if (idx < N_NODES) off[idx] = incl - v;
        __syncthreads();
        if (tid == 1023) carry_s = incl;
        __syncthreads();
    }
    if (threadIdx.x == 0) off[N_NODES] = carry_s;
}

__global__ void k_scatter(const int* __restrict__ ei, const int* __restrict__ off,
                          int* __restrict__ cur, int* __restrict__ csr_src) {
    int i = blockIdx.x * blockDim.x + threadIdx.x;
    if (i >= ETOT) return;
    int s, d;
    if (i < N_EDGES) { s = ei[i]; d = ei[N_EDGES + i]; }
    else             { s = d = i - N_EDGES; }
    int pos = off[d] + atomicAdd(&cur[d], 1);
    csr_src[pos] = s;
}

// ---------------- graph boundaries (batch is sorted): no atomics ----------------

__global__ void k_bounds(const int* __restrict__ batch, int* __restrict__ gstart) {
    int i = blockIdx.x * blockDim.x + threadIdx.x;
    if (i >= N_NODES) return;
    int b = batch[i];
    int prev = (i == 0) ? -1 : batch[i - 1];
    for (int g = prev + 1; g <= b; ++g) gstart[g] = i;
    if (i == N_NODES - 1) {
        for (int g = b + 1; g <= NGRAPH; ++g) gstart[g] = N_NODES;
    }
}

// ---------------- input projection: h = relu(x @ W_in + b_in) ----------------

__global__ __launch_bounds__(256) void k_inproj(const float* __restrict__ x,
                                                const float* __restrict__ W,
                                                const float* __restrict__ b,
                                                float* __restrict__ h) {
    __shared__ float xs[2][F_IN];
    int tid = threadIdx.x;
    int node0 = blockIdx.x * 2;
    if (tid < 2 * F_IN) {
        int r = tid / F_IN, k = tid % F_IN;
        int nd = node0 + r;
        xs[r][k] = (nd < N_NODES) ? x[nd * F_IN + k] : 0.f;
    }
    __syncthreads();
    int ln = tid >> 7;
    int c  = tid & 127;
    int node = node0 + ln;
    if (node >= N_NODES) return;
    float s = b[c];
    #pragma unroll
    for (int k = 0; k < F_IN; ++k) s += xs[ln][k] * W[k * HID + c];
    h[(size_t)node * HID + c] = fmaxf(s, 0.f);
}

// ---------------- GEMM: xl[N,512](bf16) = h[N,128](f32) @ W[128,512](f32) ----------------

__global__ __launch_bounds__(256) void k_gemm(const float* __restrict__ A,
                                              const float* __restrict__ B,
                                              unsigned short* __restrict__ C) {
    __shared__ float As[64][132];
    __shared__ float Bs[128][64];
    int row0 = blockIdx.x * 64;
    int col0 = blockIdx.y * 64;
    int tid = threadIdx.x;
    {   // stage A: 64 x 128
        int kq = (tid & 31) << 2;
        int r0 = tid >> 5;
        #pragma unroll
        for (int rr = 0; rr < 8; ++rr) {
            int r = r0 + rr * 8;
            int row = row0 + r;
            float4 v = make_float4(0.f, 0.f, 0.f, 0.f);
            if (row < N_NODES) v = *(const float4*)(A + (size_t)row * HID + kq);
            *(float4*)&As[r][kq] = v;
        }
    }
    {   // stage B: 128 x 64
        int c4 = (tid & 15) << 2;
        int k0 = tid >> 4;
        #pragma unroll
        for (int kk = 0; kk < 8; ++kk) {
            int k = k0 + kk * 16;
            *(float4*)&Bs[k][c4] = *(const float4*)(B + (size_t)k * FTOT + col0 + c4);
        }
    }
    __syncthreads();
    int tx = tid & 15, ty = tid >> 4;
    float acc[4][4] = {};
    #pragma unroll 2
    for (int k = 0; k < 128; k += 4) {
        float4 a[4], bb[4];
        #pragma unroll
        for (int i = 0; i < 4; ++i) a[i] = *(const float4*)&As[ty * 4 + i][k];
        #pragma unroll
        for (int j = 0; j < 4; ++j) bb[j] = *(const float4*)&Bs[k + j][tx * 4];
        #pragma unroll
        for (int i = 0; i < 4; ++i) {
            const float* av = (const float*)&a[i];
            #pragma unroll
            for (int j = 0; j < 4; ++j) {
                acc[i][0] += av[j] * bb[j].x;
                acc[i][1] += av[j] * bb[j].y;
                acc[i][2] += av[j] * bb[j].z;
                acc[i][3] += av[j] * bb[j].w;
            }
        }
    }
    #pragma unroll
    for (int i = 0; i < 4; ++i) {
        int row = row0 + ty * 4 + i;
        if (row < N_NODES) {
            ushort4 o;
            o.x = f2bf(acc[i][0]); o.y = f2bf(acc[i][1]);
            o.z = f2bf(acc[i][2]); o.w = f2bf(acc[i][3]);
            *(ushort4*)(C + (size_t)row * FTOT + col0 + tx * 4) = o;
        }
    }
}

// ---------------- attention coefficients per node ----------------

__global__ __launch_bounds__(256) void k_att(const unsigned short* __restrict__ xl,
                                             const float* __restrict__ asrc,
                                             const float* __restrict__ adst,
                                             float* __restrict__ al_s,
                                             float* __restrict__ al_d) {
    int wid  = threadIdx.x >> 6;
    int lane = threadIdx.x & 63;
    int node = blockIdx.x * 4 + wid;
    if (node >= N_NODES) return;
    int base = lane * 8;
    ushortx8 xv = *(const ushortx8*)(xl + (size_t)node * FTOT + base);
    float xf[8];
    #pragma unroll
    for (int j = 0; j < 8; ++j) xf[j] = bf2f(xv[j]);
    const float4* s4 = (const float4*)(asrc + base);
    const float4* d4 = (const float4*)(adst + base);
    float4 s0 = s4[0], s1 = s4[1], dd0 = d4[0], dd1 = d4[1];
    float ps = xf[0]*s0.x + xf[1]*s0.y + xf[2]*s0.z + xf[3]*s0.w
             + xf[4]*s1.x + xf[5]*s1.y + xf[6]*s1.z + xf[7]*s1.w;
    float pd = xf[0]*dd0.x + xf[1]*dd0.y + xf[2]*dd0.z + xf[3]*dd0.w
             + xf[4]*dd1.x + xf[5]*dd1.y + xf[6]*dd1.z + xf[7]*dd1.w;
    #pragma unroll
    for (int m = 1; m < 16; m <<= 1) {
        ps += __shfl_xor(ps, m, 64);
        pd += __shfl_xor(pd, m, 64);
    }
    if ((lane & 15) == 0) {
        int hh = lane >> 4;
        al_s[node * HEADS + hh] = ps;
        al_d[node * HEADS + hh] = pd;
    }
}

// ---------------- edge aggregation (segment softmax + weighted sum) ----------------

__global__ __launch_bounds__(256) void k_agg(const unsigned short* __restrict__ xl,
                                             const float* __restrict__ al_s,
                                             const float* __restrict__ al_d,
                                             const int* __restrict__ csr_off,
                                             const int* __restrict__ csr_src,
                                             const float* __restrict__ bias,
                                             float* __restrict__ h) {
    int wid  = threadIdx.x >> 6;
    int lane = threadIdx.x & 63;
    int node = blockIdx.x * 4 + wid;
    if (node >= N_NODES) return;
    int hh = lane >> 4;
    int e0 = csr_off[node], e1 = csr_off[node + 1];
    float ald = al_d[node * HEADS + hh];

    // pass A: online (m, z) for this head, edge-parallel over 16 lanes
    float m = -1e30f, z = 0.f;
    for (int e = e0 + (lane & 15); e < e1; e += 16) {
        int s = csr_src[e];
        float ev = al_s[s * HEADS + hh] + ald;
        ev = ev > 0.f ? ev : NEG_SLOPE * ev;
        float mn = fmaxf(m, ev);
        z = z * __expf(m - mn) + __expf(ev - mn);
        m = mn;
    }
    #pragma unroll
    for (int msk = 1; msk < 16; msk <<= 1) {
        float m2 = __shfl_xor(m, msk, 64);
        float z2 = __shfl_xor(z, msk, 64);
        float mn = fmaxf(m, m2);
        z = z * __expf(m - mn) + z2 * __expf(m2 - mn);
        m = mn;
    }
    float zinv = 1.f / (z + 1e-16f);

    // pass B: accumulate alpha * xl[src] (bf16 gather, 16 B/lane/edge)
    float acc[8] = {};
    #pragma unroll 2
    for (int e = e0; e < e1; ++e) {
        int s = csr_src[e];
        float ev = al_s[s * HEADS + hh] + ald;
        ev = ev > 0.f ? ev : NEG_SLOPE * ev;
        float alpha = __expf(ev - m) * zinv;
        ushortx8 v = *(const ushortx8*)(xl + (size_t)s * FTOT + lane * 8);
        #pragma unroll
        for (int j = 0; j < 8; ++j) acc[j] += alpha * bf2f(v[j]);
    }
    #pragma unroll
    for (int j = 0; j < 8; ++j) {
        acc[j] += __shfl_xor(acc[j], 16, 64);
        acc[j] += __shfl_xor(acc[j], 32, 64);
    }
    if (lane < 16) {
        int c = lane * 8;
        float4 hv0 = *(const float4*)(h + (size_t)node * HID + c);
        float4 hv1 = *(const float4*)(h + (size_t)node * HID + c + 4);
        float4 b0 = *(const float4*)(bias + c);
        float4 b1 = *(const float4*)(bias + c + 4);
        float4 o0, o1;
        o0.x = fmaxf(acc[0] * 0.25f + b0.x, 0.f) + hv0.x;
        o0.y = fmaxf(acc[1] * 0.25f + b0.y, 0.f) + hv0.y;
        o0.z = fmaxf(acc[2] * 0.25f + b0.z, 0.f) + hv0.z;
        o0.w = fmaxf(acc[3] * 0.25f + b0.w, 0.f) + hv0.w;
        o1.x = fmaxf(acc[4] * 0.25f + b1.x, 0.f) + hv1.x;
        o1.y = fmaxf(acc[5] * 0.25f + b1.y, 0.f) + hv1.y;
        o1.z = fmaxf(acc[6] * 0.25f + b1.z, 0.f) + hv1.z;
        o1.w = fmaxf(acc[7] * 0.25f + b1.w, 0.f) + hv1.w;
        *(float4*)(h + (size_t)node * HID + c)     = o0;
        *(float4*)(h + (size_t)node * HID + c + 4) = o1;
    }
}

// ---------------- pooling + MLP ----------------

__global__ __launch_bounds__(128) void k_pool(const float* __restrict__ h,
                                              const int* __restrict__ gstart,
                                              float* __restrict__ pooled) {
    int g = blockIdx.y;
    int slice = blockIdx.x;      // 0..31
    int tid = threadIdx.x;       // 0..127
    int start = gstart[g];
    int cnt   = gstart[g + 1] - start;
    int per = (cnt + 31) / 32;
    int r0 = slice * per, r1 = min(r0 + per, cnt);
    if (r0 >= r1) return;
    float s0 = 0.f, s1 = 0.f, s2 = 0.f, s3 = 0.f;
    int r = r0;
    for (; r + 3 < r1; r += 4) {
        s0 += h[(size_t)(start + r)     * HID + tid];
        s1 += h[(size_t)(start + r + 1) * HID + tid];
        s2 += h[(size_t)(start + r + 2) * HID + tid];
        s3 += h[(size_t)(start + r + 3) * HID + tid];
    }
    for (; r < r1; ++r) s0 += h[(size_t)(start + r) * HID + tid];
    atomicAdd(&pooled[g * HID + tid], (s0 + s1) + (s2 + s3));
}

__global__ __launch_bounds__(256) void k_mlp(const float* __restrict__ pooled,
                                             const int* __restrict__ gstart,
                                             const float* __restrict__ W1, const float* __restrict__ b1,
                                             const float* __restrict__ W2, const float* __restrict__ b2,
                                             const float* __restrict__ W3, const float* __restrict__ b3,
                                             float* __restrict__ out) {
    __shared__ float g[NGRAPH][HID];
    __shared__ float t1[NGRAPH][64];
    __shared__ float t2[NGRAPH][64];
    int tid = threadIdx.x;
    for (int i = tid; i < NGRAPH * HID; i += 256) {
        int gr = i >> 7;
        float inv = 1.f / fmaxf((float)(gstart[gr + 1] - gstart[gr]), 1.f);
        g[gr][i & 127] = pooled[i] * inv;
    }
    __syncthreads();
    for (int i = tid; i < NGRAPH * 64; i += 256) {
        int r = i >> 6, c = i & 63;
        float s = b1[c];
        #pragma unroll 4
        for (int k = 0; k < HID; ++k) s += g[r][k] * W1[k * 64 + c];
        t1[r][c] = fmaxf(s, 0.f);
    }
    __syncthreads();
    for (int i = tid; i < NGRAPH * 64; i += 256) {
        int r = i >> 6, c = i & 63;
        float s = b2[c];
        #pragma unroll 4
        for (int k = 0; k < 64; ++k) s += t1[r][k] * W2[k * 64 + c];
        t2[r][c] = fmaxf(s, 0.f);
    }
    __syncthreads();
    for (int i = tid; i < NGRAPH * 32; i += 256) {
        int r = i >> 5, c = i & 31;
        float s = b3[c];
        #pragma unroll 4
        for (int k = 0; k < 64; ++k) s += t2[r][k] * W3[k * 32 + c];
        out[i] = s;
    }
}

// ---------------- launcher ----------------

extern "C" void kernel_launch(void* const* d_in, const int* in_sizes, int n_in,
                              void* d_out, int out_size, void* d_ws, size_t ws_size,
                              hipStream_t stream) {
    const float* x       = (const float*)d_in[0];
    const int*   ei      = (const int*)d_in[1];
    const int*   batch   = (const int*)d_in[2];
    const float* W_in    = (const float*)d_in[3];
    const float* b_in    = (const float*)d_in[4];
    const float* gat_W   = (const float*)d_in[5];
    const float* att_src = (const float*)d_in[6];
    const float* att_dst = (const float*)d_in[7];
    const float* gat_b   = (const float*)d_in[8];
    const float* W1 = (const float*)d_in[9];
    const float* b1 = (const float*)d_in[10];
    const float* W2 = (const float*)d_in[11];
    const float* b2 = (const float*)d_in[12];
    const float* W3 = (const float*)d_in[13];
    const float* b3 = (const float*)d_in[14];
    float* out = (float*)d_out;

    char* ws = (char*)d_ws;
    size_t o = 0;
    auto alloc = [&](size_t nbytes) -> void* {
        void* p = ws + o;
        o += (nbytes + 255) & ~(size_t)255;
        return p;
    };
    int* deg      = (int*)alloc((size_t)2 * N_NODES * 4);      // deg | cur
    int* cur      = deg + N_NODES;
    int* gstart   = (int*)alloc((size_t)(NGRAPH + 1) * 4);
    float* pooled = (float*)alloc((size_t)NGRAPH * HID * 4);
    int* csr_off  = (int*)alloc((size_t)(N_NODES + 1) * 4);
    int* csr_src  = (int*)alloc((size_t)ETOT * 4);
    float* h      = (float*)alloc((size_t)N_NODES * HID * 4);
    unsigned short* xl = (unsigned short*)alloc((size_t)N_NODES * FTOT * 2);
    float* al_s   = (float*)alloc((size_t)N_NODES * HEADS * 4);
    float* al_d   = (float*)alloc((size_t)N_NODES * HEADS * 4);

    hipMemsetAsync(deg, 0, (size_t)2 * N_NODES * 4, stream);
    hipMemsetAsync(pooled, 0, (size_t)NGRAPH * HID * 4, stream);

    k_hist<<<(ETOT + 255) / 256, 256, 0, stream>>>(ei, deg);
    k_scan<<<1, 1024, 0, stream>>>(deg, csr_off);
    k_scatter<<<(ETOT + 255) / 256, 256, 0, stream>>>(ei, csr_off, cur, csr_src);
    k_bounds<<<(N_NODES + 255) / 256, 256, 0, stream>>>(batch, gstart);

    k_inproj<<<(N_NODES + 1) / 2, 256, 0, stream>>>(x, W_in, b_in, h);

    for (int l = 0; l < LAYERS; ++l) {
        k_gemm<<<dim3((N_NODES + 63) / 64, FTOT / 64), 256, 0, stream>>>(
            h, gat_W + (size_t)l * HID * FTOT, xl);
        k_att<<<(N_NODES + 3) / 4, 256, 0, stream>>>(
            xl, att_src + (size_t)l * HEADS * HID, att_dst + (size_t)l * HEADS * HID, al_s, al_d);
        k_agg<<<(N_NODES + 3) / 4, 256, 0, stream>>>(
            xl, al_s, al_d, csr_off, csr_src, gat_b + (size_t)l * HID, h);
    }

    k_pool<<<dim3(32, NGRAPH), 128, 0, stream>>>(h, gstart, pooled);
    k_mlp<<<1, 256, 0, stream>>>(pooled, gstart, W1, b1, W2, b2, W3, b3, out);
}

// Round 5
// 378.791 us; speedup vs baseline: 2.1309x; 1.4032x over previous
//
#include <hip/hip_runtime.h>

#define N_NODES 20000
#define N_PAD   20032            // 313 * 64
#define N_EDGES 200000
#define ETOT    (N_EDGES + N_NODES)
#define F_IN    20
#define HID     128
#define HEADS   4
#define FTOT    (HEADS * HID)   // 512
#define LAYERS  4
#define NGRAPH  32
#define NEG_SLOPE 0.2f

typedef __attribute__((ext_vector_type(8))) unsigned short ushortx8;
typedef __attribute__((ext_vector_type(8))) short short8;
typedef __attribute__((ext_vector_type(4))) float f32x4;

static __device__ __forceinline__ unsigned short f2bf(float f) {
    unsigned u = __float_as_uint(f);
    u += 0x7FFFu + ((u >> 16) & 1u);   // round-to-nearest-even
    return (unsigned short)(u >> 16);
}
static __device__ __forceinline__ float bf2f(unsigned short s) {
    return __uint_as_float(((unsigned)s) << 16);
}

// ---------------- CSR build (dst is layer-invariant) ----------------

__global__ void k_hist(const int* __restrict__ ei, int* __restrict__ deg) {
    int i = blockIdx.x * blockDim.x + threadIdx.x;
    if (i >= ETOT) return;
    int d = (i < N_EDGES) ? ei[N_EDGES + i] : (i - N_EDGES);
    atomicAdd(&deg[d], 1);
}

__global__ __launch_bounds__(1024) void k_scan(const int* __restrict__ deg, int* __restrict__ off) {
    __shared__ int wsum[16];
    __shared__ int carry_s;
    int tid  = threadIdx.x;
    int lane = tid & 63, wv = tid >> 6;
    if (tid == 0) carry_s = 0;
    __syncthreads();
    for (int base = 0; base < N_NODES; base += 1024) {
        int idx = base + tid;
        int v = (idx < N_NODES) ? deg[idx] : 0;
        int x = v;
        #pragma unroll
        for (int s = 1; s < 64; s <<= 1) {
            int t = __shfl_up(x, s, 64);
            if (lane >= s) x += t;
        }
        if (lane == 63) wsum[wv] = x;
        __syncthreads();
        if (wv == 0) {
            int ws = (lane < 16) ? wsum[lane] : 0;
            #pragma unroll
            for (int s = 1; s < 16; s <<= 1) {
                int t = __shfl_up(ws, s, 64);
                if (lane >= s) ws += t;
            }
            if (lane < 16) wsum[lane] = ws;
        }
        __syncthreads();
        int wprev = (wv == 0) ? 0 : wsum[wv - 1];
        int incl  = carry_s + wprev + x;
        if (idx < N_NODES) off[idx] = incl - v;
        __syncthreads();
        if (tid == 1023) carry_s = incl;
        __syncthreads();
    }
    if (threadIdx.x == 0) off[N_NODES] = carry_s;
}

__global__ void k_scatter(const int* __restrict__ ei, const int* __restrict__ off,
                          int* __restrict__ cur, int* __restrict__ csr_src) {
    int i = blockIdx.x * blockDim.x + threadIdx.x;
    if (i >= ETOT) return;
    int s, d;
    if (i < N_EDGES) { s = ei[i]; d = ei[N_EDGES + i]; }
    else             { s = d = i - N_EDGES; }
    int pos = off[d] + atomicAdd(&cur[d], 1);
    csr_src[pos] = s;
}

// ---------------- graph boundaries (batch is sorted): no atomics ----------------

__global__ void k_bounds(const int* __restrict__ batch, int* __restrict__ gstart) {
    int i = blockIdx.x * blockDim.x + threadIdx.x;
    if (i >= N_NODES) return;
    int b = batch[i];
    int prev = (i == 0) ? -1 : batch[i - 1];
    for (int g = prev + 1; g <= b; ++g) gstart[g] = i;
    if (i == N_NODES - 1) {
        for (int g = b + 1; g <= NGRAPH; ++g) gstart[g] = N_NODES;
    }
}

// ---------------- W pre-swizzle: gat_W fp32 -> bf16 MFMA-fragment order ----------------
// layout: [l][cg(32)][kc(4)][lane(64)][e(8)],
// value = W[l][kc*32 + (lane>>4)*8 + e][cg*16 + (lane&15)]

__global__ void k_wconv(const float* __restrict__ W, unsigned short* __restrict__ wswz) {
    int o = blockIdx.x * 256 + threadIdx.x;
    if (o >= LAYERS * 32 * 4 * 64 * 8) return;
    int e    = o & 7;
    int lane = (o >> 3) & 63;
    int kc   = (o >> 9) & 3;
    int cg   = (o >> 11) & 31;
    int l    = o >> 16;
    int k    = kc * 32 + (lane >> 4) * 8 + e;
    int col  = cg * 16 + (lane & 15);
    wswz[o] = f2bf(W[((size_t)l * HID + k) * FTOT + col]);
}

// ---------------- input projection: h = relu(x @ W_in + b_in), + bf16 shadow ----------------

__global__ __launch_bounds__(256) void k_inproj(const float* __restrict__ x,
                                                const float* __restrict__ W,
                                                const float* __restrict__ b,
                                                float* __restrict__ h,
                                                unsigned short* __restrict__ hb) {
    __shared__ float xs[2][F_IN];
    int tid = threadIdx.x;
    int node0 = blockIdx.x * 2;
    if (tid < 2 * F_IN) {
        int r = tid / F_IN, k = tid % F_IN;
        int nd = node0 + r;
        xs[r][k] = (nd < N_NODES) ? x[nd * F_IN + k] : 0.f;
    }
    __syncthreads();
    int ln = tid >> 7;
    int c  = tid & 127;
    int node = node0 + ln;
    if (node >= N_NODES) return;
    float s = b[c];
    #pragma unroll
    for (int k = 0; k < F_IN; ++k) s += xs[ln][k] * W[k * HID + c];
    float r = fmaxf(s, 0.f);
    h[(size_t)node * HID + c] = r;
    hb[(size_t)node * HID + c] = f2bf(r);
}

// ---------------- GEMM (MFMA): xl[N,512](bf16) = hb[N,128](bf16) @ wswz ----------------
// block: 256 thr = 4 waves; wave w: rows [bx*64+w*16, +16), cols [by*64, +64)

__global__ __launch_bounds__(256) void k_gemm(const unsigned short* __restrict__ hb,
                                              const unsigned short* __restrict__ wswz,
                                              unsigned short* __restrict__ xl) {
    int tid  = threadIdx.x;
    int lane = tid & 63;
    int w    = tid >> 6;
    int r0   = blockIdx.x * 64 + w * 16;
    int cgb  = blockIdx.y * 4;
    int arow = r0 + (lane & 15);
    const short8* ap = (const short8*)(hb + (size_t)arow * HID + (lane >> 4) * 8);
    const short8* bp = (const short8*)wswz;
    short8 a[4];
    #pragma unroll
    for (int kc = 0; kc < 4; ++kc) a[kc] = ap[kc * 4];   // kc*32 shorts
    f32x4 acc[4];
    #pragma unroll
    for (int ct = 0; ct < 4; ++ct) {
        f32x4 c = {0.f, 0.f, 0.f, 0.f};
        int cg = cgb + ct;
        #pragma unroll
        for (int kc = 0; kc < 4; ++kc) {
            short8 b = bp[(cg * 4 + kc) * 64 + lane];
            c = __builtin_amdgcn_mfma_f32_16x16x32_bf16(a[kc], b, c, 0, 0, 0);
        }
        acc[ct] = c;
    }
    int orow = r0 + (lane >> 4) * 4;
    int ocol = lane & 15;
    #pragma unroll
    for (int ct = 0; ct < 4; ++ct) {
        int col = (cgb + ct) * 16 + ocol;
        #pragma unroll
        for (int r = 0; r < 4; ++r) {
            int row = orow + r;
            if (row < N_NODES) xl[(size_t)row * FTOT + col] = f2bf(acc[ct][r]);
        }
    }
}

// ---------------- attention coefficients per node ----------------

__global__ __launch_bounds__(256) void k_att(const unsigned short* __restrict__ xl,
                                             const float* __restrict__ asrc,
                                             const float* __restrict__ adst,
                                             float* __restrict__ al_s,
                                             float* __restrict__ al_d) {
    int wid  = threadIdx.x >> 6;
    int lane = threadIdx.x & 63;
    int node = blockIdx.x * 4 + wid;
    if (node >= N_NODES) return;
    int base = lane * 8;
    ushortx8 xv = *(const ushortx8*)(xl + (size_t)node * FTOT + base);
    float xf[8];
    #pragma unroll
    for (int j = 0; j < 8; ++j) xf[j] = bf2f(xv[j]);
    const float4* s4 = (const float4*)(asrc + base);
    const float4* d4 = (const float4*)(adst + base);
    float4 s0 = s4[0], s1 = s4[1], dd0 = d4[0], dd1 = d4[1];
    float ps = xf[0]*s0.x + xf[1]*s0.y + xf[2]*s0.z + xf[3]*s0.w
             + xf[4]*s1.x + xf[5]*s1.y + xf[6]*s1.z + xf[7]*s1.w;
    float pd = xf[0]*dd0.x + xf[1]*dd0.y + xf[2]*dd0.z + xf[3]*dd0.w
             + xf[4]*dd1.x + xf[5]*dd1.y + xf[6]*dd1.z + xf[7]*dd1.w;
    #pragma unroll
    for (int m = 1; m < 16; m <<= 1) {
        ps += __shfl_xor(ps, m, 64);
        pd += __shfl_xor(pd, m, 64);
    }
    if ((lane & 15) == 0) {
        int hh = lane >> 4;
        al_s[node * HEADS + hh] = ps;
        al_d[node * HEADS + hh] = pd;
    }
}

// ---------------- edge aggregation (segment softmax + weighted sum) ----------------

__global__ __launch_bounds__(256) void k_agg(const unsigned short* __restrict__ xl,
                                             const float* __restrict__ al_s,
                                             const float* __restrict__ al_d,
                                             const int* __restrict__ csr_off,
                                             const int* __restrict__ csr_src,
                                             const float* __restrict__ bias,
                                             float* __restrict__ h,
                                             unsigned short* __restrict__ hb) {
    int wid  = threadIdx.x >> 6;
    int lane = threadIdx.x & 63;
    int node = blockIdx.x * 4 + wid;
    if (node >= N_NODES) return;
    int hh = lane >> 4;
    int e0 = csr_off[node], e1 = csr_off[node + 1];
    float ald = al_d[node * HEADS + hh];

    float m = -1e30f, z = 0.f;
    for (int e = e0 + (lane & 15); e < e1; e += 16) {
        int s = csr_src[e];
        float ev = al_s[s * HEADS + hh] + ald;
        ev = ev > 0.f ? ev : NEG_SLOPE * ev;
        float mn = fmaxf(m, ev);
        z = z * __expf(m - mn) + __expf(ev - mn);
        m = mn;
    }
    #pragma unroll
    for (int msk = 1; msk < 16; msk <<= 1) {
        float m2 = __shfl_xor(m, msk, 64);
        float z2 = __shfl_xor(z, msk, 64);
        float mn = fmaxf(m, m2);
        z = z * __expf(m - mn) + z2 * __expf(m2 - mn);
        m = mn;
    }
    float zinv = 1.f / (z + 1e-16f);

    float acc[8] = {};
    #pragma unroll 2
    for (int e = e0; e < e1; ++e) {
        int s = csr_src[e];
        float ev = al_s[s * HEADS + hh] + ald;
        ev = ev > 0.f ? ev : NEG_SLOPE * ev;
        float alpha = __expf(ev - m) * zinv;
        ushortx8 v = *(const ushortx8*)(xl + (size_t)s * FTOT + lane * 8);
        #pragma unroll
        for (int j = 0; j < 8; ++j) acc[j] += alpha * bf2f(v[j]);
    }
    #pragma unroll
    for (int j = 0; j < 8; ++j) {
        acc[j] += __shfl_xor(acc[j], 16, 64);
        acc[j] += __shfl_xor(acc[j], 32, 64);
    }
    if (lane < 16) {
        int c = lane * 8;
        float4 hv0 = *(const float4*)(h + (size_t)node * HID + c);
        float4 hv1 = *(const float4*)(h + (size_t)node * HID + c + 4);
        float4 b0 = *(const float4*)(bias + c);
        float4 b1 = *(const float4*)(bias + c + 4);
        float4 o0, o1;
        o0.x = fmaxf(acc[0] * 0.25f + b0.x, 0.f) + hv0.x;
        o0.y = fmaxf(acc[1] * 0.25f + b0.y, 0.f) + hv0.y;
        o0.z = fmaxf(acc[2] * 0.25f + b0.z, 0.f) + hv0.z;
        o0.w = fmaxf(acc[3] * 0.25f + b0.w, 0.f) + hv0.w;
        o1.x = fmaxf(acc[4] * 0.25f + b1.x, 0.f) + hv1.x;
        o1.y = fmaxf(acc[5] * 0.25f + b1.y, 0.f) + hv1.y;
        o1.z = fmaxf(acc[6] * 0.25f + b1.z, 0.f) + hv1.z;
        o1.w = fmaxf(acc[7] * 0.25f + b1.w, 0.f) + hv1.w;
        *(float4*)(h + (size_t)node * HID + c)     = o0;
        *(float4*)(h + (size_t)node * HID + c + 4) = o1;
        ushortx8 hv;
        hv[0] = f2bf(o0.x); hv[1] = f2bf(o0.y); hv[2] = f2bf(o0.z); hv[3] = f2bf(o0.w);
        hv[4] = f2bf(o1.x); hv[5] = f2bf(o1.y); hv[6] = f2bf(o1.z); hv[7] = f2bf(o1.w);
        *(ushortx8*)(hb + (size_t)node * HID + c) = hv;
    }
}

// ---------------- pooling + MLP ----------------

__global__ __launch_bounds__(128) void k_pool(const float* __restrict__ h,
                                              const int* __restrict__ gstart,
                                              float* __restrict__ pooled) {
    int g = blockIdx.y;
    int slice = blockIdx.x;      // 0..31
    int tid = threadIdx.x;       // 0..127
    int start = gstart[g];
    int cnt   = gstart[g + 1] - start;
    int per = (cnt + 31) / 32;
    int r0 = slice * per, r1 = min(r0 + per, cnt);
    if (r0 >= r1) return;
    float s0 = 0.f, s1 = 0.f, s2 = 0.f, s3 = 0.f;
    int r = r0;
    for (; r + 3 < r1; r += 4) {
        s0 += h[(size_t)(start + r)     * HID + tid];
        s1 += h[(size_t)(start + r + 1) * HID + tid];
        s2 += h[(size_t)(start + r + 2) * HID + tid];
        s3 += h[(size_t)(start + r + 3) * HID + tid];
    }
    for (; r < r1; ++r) s0 += h[(size_t)(start + r) * HID + tid];
    atomicAdd(&pooled[g * HID + tid], (s0 + s1) + (s2 + s3));
}

// one block per graph; 256 threads; k-split partials reduced in LDS
__global__ __launch_bounds__(256) void k_mlp(const float* __restrict__ pooled,
                                             const int* __restrict__ gstart,
                                             const float* __restrict__ W1, const float* __restrict__ b1,
                                             const float* __restrict__ W2, const float* __restrict__ b2,
                                             const float* __restrict__ W3, const float* __restrict__ b3,
                                             float* __restrict__ out) {
    int gr = blockIdx.x;
    __shared__ float g[HID];
    __shared__ float part[4][64];
    __shared__ float t1[64], t2[64];
    int tid = threadIdx.x;
    if (tid < HID) {
        float inv = 1.f / fmaxf((float)(gstart[gr + 1] - gstart[gr]), 1.f);
        g[tid] = pooled[gr * HID + tid] * inv;
    }
    __syncthreads();
    {   // t1 = relu(g @ W1 + b1), K=128 split 4x32
        int c = tid & 63, q = tid >> 6;
        float s = 0.f;
        #pragma unroll 8
        for (int k = q * 32; k < q * 32 + 32; ++k) s += g[k] * W1[k * 64 + c];
        part[q][c] = s;
        __syncthreads();
        if (tid < 64) t1[tid] = fmaxf(part[0][tid] + part[1][tid] + part[2][tid] + part[3][tid] + b1[tid], 0.f);
        __syncthreads();
    }
    {   // t2 = relu(t1 @ W2 + b2), K=64 split 4x16
        int c = tid & 63, q = tid >> 6;
        float s = 0.f;
        #pragma unroll 8
        for (int k = q * 16; k < q * 16 + 16; ++k) s += t1[k] * W2[k * 64 + c];
        part[q][c] = s;
        __syncthreads();
        if (tid < 64) t2[tid] = fmaxf(part[0][tid] + part[1][tid] + part[2][tid] + part[3][tid] + b2[tid], 0.f);
        __syncthreads();
    }
    {   // out = t2 @ W3 + b3, K=64 split 8x8
        int c = tid & 31, q = tid >> 5;
        float s = 0.f;
        #pragma unroll 8
        for (int k = q * 8; k < q * 8 + 8; ++k) s += t2[k] * W3[k * 32 + c];
        float* pf = &part[0][0];
        pf[q * 32 + c] = s;
        __syncthreads();
        if (tid < 32) {
            float r = b3[tid];
            #pragma unroll
            for (int q2 = 0; q2 < 8; ++q2) r += pf[q2 * 32 + tid];
            out[gr * 32 + tid] = r;
        }
    }
}

// ---------------- launcher ----------------

extern "C" void kernel_launch(void* const* d_in, const int* in_sizes, int n_in,
                              void* d_out, int out_size, void* d_ws, size_t ws_size,
                              hipStream_t stream) {
    const float* x       = (const float*)d_in[0];
    const int*   ei      = (const int*)d_in[1];
    const int*   batch   = (const int*)d_in[2];
    const float* W_in    = (const float*)d_in[3];
    const float* b_in    = (const float*)d_in[4];
    const float* gat_W   = (const float*)d_in[5];
    const float* att_src = (const float*)d_in[6];
    const float* att_dst = (const float*)d_in[7];
    const float* gat_b   = (const float*)d_in[8];
    const float* W1 = (const float*)d_in[9];
    const float* b1 = (const float*)d_in[10];
    const float* W2 = (const float*)d_in[11];
    const float* b2 = (const float*)d_in[12];
    const float* W3 = (const float*)d_in[13];
    const float* b3 = (const float*)d_in[14];
    float* out = (float*)d_out;

    char* ws = (char*)d_ws;
    size_t o = 0;
    auto alloc = [&](size_t nbytes) -> void* {
        void* p = ws + o;
        o += (nbytes + 255) & ~(size_t)255;
        return p;
    };
    int* deg      = (int*)alloc((size_t)2 * N_NODES * 4);      // deg | cur
    int* cur      = deg + N_NODES;
    int* gstart   = (int*)alloc((size_t)(NGRAPH + 1) * 4);
    float* pooled = (float*)alloc((size_t)NGRAPH * HID * 4);
    int* csr_off  = (int*)alloc((size_t)(N_NODES + 1) * 4);
    int* csr_src  = (int*)alloc((size_t)ETOT * 4);
    float* h      = (float*)alloc((size_t)N_NODES * HID * 4);
    unsigned short* hb   = (unsigned short*)alloc((size_t)N_PAD * HID * 2);
    unsigned short* xl   = (unsigned short*)alloc((size_t)N_NODES * FTOT * 2);
    unsigned short* wswz = (unsigned short*)alloc((size_t)LAYERS * HID * FTOT * 2);
    float* al_s   = (float*)alloc((size_t)N_NODES * HEADS * 4);
    float* al_d   = (float*)alloc((size_t)N_NODES * HEADS * 4);

    hipMemsetAsync(deg, 0, (size_t)2 * N_NODES * 4, stream);
    hipMemsetAsync(pooled, 0, (size_t)NGRAPH * HID * 4, stream);

    k_hist<<<(ETOT + 255) / 256, 256, 0, stream>>>(ei, deg);
    k_scan<<<1, 1024, 0, stream>>>(deg, csr_off);
    k_scatter<<<(ETOT + 255) / 256, 256, 0, stream>>>(ei, csr_off, cur, csr_src);
    k_bounds<<<(N_NODES + 255) / 256, 256, 0, stream>>>(batch, gstart);
    k_wconv<<<(LAYERS * 32 * 4 * 64 * 8) / 256, 256, 0, stream>>>(gat_W, wswz);

    k_inproj<<<(N_NODES + 1) / 2, 256, 0, stream>>>(x, W_in, b_in, h, hb);

    for (int l = 0; l < LAYERS; ++l) {
        k_gemm<<<dim3(N_PAD / 64, FTOT / 64), 256, 0, stream>>>(
            hb, wswz + (size_t)l * HID * FTOT, xl);
        k_att<<<(N_NODES + 3) / 4, 256, 0, stream>>>(
            xl, att_src + (size_t)l * HEADS * HID, att_dst + (size_t)l * HEADS * HID, al_s, al_d);
        k_agg<<<(N_NODES + 3) / 4, 256, 0, stream>>>(
            xl, al_s, al_d, csr_off, csr_src, gat_b + (size_t)l * HID, h, hb);
    }

    k_pool<<<dim3(32, NGRAPH), 128, 0, stream>>>(h, gstart, pooled);
    k_mlp<<<NGRAPH, 256, 0, stream>>>(pooled, gstart, W1, b1, W2, b2, W3, b3, out);
}